// Round 1
// baseline (668.169 us; speedup 1.0000x reference)
//
#include <hip/hip_runtime.h>
#include <math.h>

// ---------------------------------------------------------------------------
// GCN (2->64->32) + edge MLP (65->16->1), N=100k nodes, E=1.6M edges.
// Algebraic restructure:
//   L1: aggregate 2-dim scaled inputs, then W1  (2 atomics/edge not 64)
//   L2: apply W2 per node first, aggregate 32-dim (32 atomics/edge)
//   edge MLP: mW1 = [A(32x16); B(32x16); c(1x16)]; precompute u=h@A, v=h@B
//             per node; per edge hid = relu(u[row]+v[col]+ea*c+mb1)
// ---------------------------------------------------------------------------

__global__ void k_deg(const int* __restrict__ col, float* __restrict__ deg, int E) {
    int stride = gridDim.x * blockDim.x;
    for (int e = blockIdx.x * blockDim.x + threadIdx.x; e < E; e += stride)
        atomicAdd(deg + col[e], 1.0f);
}

// deg -> dinv (in place), xs = x*dinv, accx = xs (self-loop term)
__global__ void k_node1(const float* __restrict__ x, float* __restrict__ dinv,
                        float* __restrict__ xs, float* __restrict__ accx, int N) {
    int stride = gridDim.x * blockDim.x;
    for (int n = blockIdx.x * blockDim.x + threadIdx.x; n < N; n += stride) {
        float d  = dinv[n] + 1.0f;          // +1 self-loop
        float di = 1.0f / sqrtf(d);
        dinv[n]  = di;
        float x0 = x[2 * n] * di, x1 = x[2 * n + 1] * di;
        xs[2 * n] = x0;  xs[2 * n + 1] = x1;
        accx[2 * n] = x0; accx[2 * n + 1] = x1;
    }
}

__global__ void k_scat1(const int* __restrict__ row, const int* __restrict__ col,
                        const float* __restrict__ xs, float* __restrict__ accx, int E) {
    int stride = gridDim.x * blockDim.x;
    for (int e = blockIdx.x * blockDim.x + threadIdx.x; e < E; e += stride) {
        int r = row[e], c = col[e];
        float v0 = xs[2 * r], v1 = xs[2 * r + 1];
        atomicAdd(accx + 2 * c, v0);
        atomicAdd(accx + 2 * c + 1, v1);
    }
}

// out1 = relu(accx*dinv @ W1 + b1); hs2 = (out1 @ W2) * dinv; acc2 = hs2
__global__ void k_node2(const float* __restrict__ accx, const float* __restrict__ dinv,
                        const float* __restrict__ W1, const float* __restrict__ b1,
                        const float* __restrict__ W2,
                        float* __restrict__ hs2, float* __restrict__ acc2, int N) {
    __shared__ float sW1[128], sb1[64], sW2[2048];
    for (int i = threadIdx.x; i < 128;  i += blockDim.x) sW1[i] = W1[i];
    for (int i = threadIdx.x; i < 64;   i += blockDim.x) sb1[i] = b1[i];
    for (int i = threadIdx.x; i < 2048; i += blockDim.x) sW2[i] = W2[i];
    __syncthreads();
    int stride = gridDim.x * blockDim.x;
    for (int n = blockIdx.x * blockDim.x + threadIdx.x; n < N; n += stride) {
        float di = dinv[n];
        float a0 = accx[2 * n] * di, a1 = accx[2 * n + 1] * di;
        float acc[32];
#pragma unroll
        for (int j = 0; j < 32; ++j) acc[j] = 0.0f;
        for (int k = 0; k < 64; ++k) {
            float h = fmaxf(fmaf(a0, sW1[k], fmaf(a1, sW1[64 + k], sb1[k])), 0.0f);
#pragma unroll
            for (int j = 0; j < 32; ++j) acc[j] = fmaf(h, sW2[k * 32 + j], acc[j]);
        }
#pragma unroll
        for (int j = 0; j < 32; ++j) {
            float vv = acc[j] * di;
            hs2[(long long)n * 32 + j]  = vv;
            acc2[(long long)n * 32 + j] = vv;
        }
    }
}

// 32 lanes per edge: acc2[col][ch] += hs2[row][ch]
__global__ void k_scat2(const int* __restrict__ row, const int* __restrict__ col,
                        const float* __restrict__ hs2, float* __restrict__ acc2, int E) {
    long long total  = (long long)E * 32;
    long long stride = (long long)gridDim.x * blockDim.x;
    for (long long idx = (long long)blockIdx.x * blockDim.x + threadIdx.x;
         idx < total; idx += stride) {
        int e  = (int)(idx >> 5);
        int ch = (int)(idx & 31);
        int r = row[e], c = col[e];
        atomicAdd(acc2 + (long long)c * 32 + ch, hs2[(long long)r * 32 + ch]);
    }
}

// h2 = relu(acc2*dinv + b2); u = h2 @ A; v = h2 @ B  (A/B = mW1 rows 0..31/32..63)
__global__ void k_node3(const float* __restrict__ acc2, const float* __restrict__ dinv,
                        const float* __restrict__ b2, const float* __restrict__ mW1,
                        float* __restrict__ u, float* __restrict__ v, int N) {
    __shared__ float sA[512], sB[512], sb2[32];
    for (int i = threadIdx.x; i < 512; i += blockDim.x) { sA[i] = mW1[i]; sB[i] = mW1[512 + i]; }
    for (int i = threadIdx.x; i < 32;  i += blockDim.x) sb2[i] = b2[i];
    __syncthreads();
    int stride = gridDim.x * blockDim.x;
    for (int n = blockIdx.x * blockDim.x + threadIdx.x; n < N; n += stride) {
        float di = dinv[n];
        // vectorized read of this node's 32 aggregated channels
        float rbuf[32];
        const float4* ap = (const float4*)(acc2 + (long long)n * 32);
#pragma unroll
        for (int q = 0; q < 8; ++q) {
            float4 t = ap[q];
            rbuf[4 * q + 0] = t.x; rbuf[4 * q + 1] = t.y;
            rbuf[4 * q + 2] = t.z; rbuf[4 * q + 3] = t.w;
        }
        float ua[16], va[16];
#pragma unroll
        for (int i = 0; i < 16; ++i) { ua[i] = 0.0f; va[i] = 0.0f; }
        for (int j = 0; j < 32; ++j) {
            float h = fmaxf(fmaf(rbuf[j], di, sb2[j]), 0.0f);
#pragma unroll
            for (int i = 0; i < 16; ++i) {
                ua[i] = fmaf(h, sA[j * 16 + i], ua[i]);
                va[i] = fmaf(h, sB[j * 16 + i], va[i]);
            }
        }
#pragma unroll
        for (int i = 0; i < 16; ++i) {
            u[(long long)n * 16 + i] = ua[i];
            v[(long long)n * 16 + i] = va[i];
        }
    }
}

__global__ void k_edge(const int* __restrict__ row, const int* __restrict__ col,
                       const float* __restrict__ ea,
                       const float* __restrict__ u, const float* __restrict__ v,
                       const float* __restrict__ mW1, const float* __restrict__ mb1,
                       const float* __restrict__ mW2, const float* __restrict__ mb2,
                       float* __restrict__ out, int E) {
    __shared__ float sC[16], sb1[16], sW2v[16], sb2s;
    if (threadIdx.x < 16) {
        sC[threadIdx.x]   = mW1[64 * 16 + threadIdx.x];  // edge_attr row of mW1
        sb1[threadIdx.x]  = mb1[threadIdx.x];
        sW2v[threadIdx.x] = mW2[threadIdx.x];
    }
    if (threadIdx.x == 0) sb2s = mb2[0];
    __syncthreads();
    int stride = gridDim.x * blockDim.x;
    for (int e = blockIdx.x * blockDim.x + threadIdx.x; e < E; e += stride) {
        int r = row[e], c = col[e];
        float a = ea[e];
        const float4* up = (const float4*)(u + (long long)r * 16);
        const float4* vp = (const float4*)(v + (long long)c * 16);
        float s = sb2s;
#pragma unroll
        for (int q = 0; q < 4; ++q) {
            float4 uu = up[q];
            float4 vv = vp[q];
            float h;
            h = fmaxf(uu.x + vv.x + fmaf(a, sC[4 * q + 0], sb1[4 * q + 0]), 0.0f);
            s = fmaf(h, sW2v[4 * q + 0], s);
            h = fmaxf(uu.y + vv.y + fmaf(a, sC[4 * q + 1], sb1[4 * q + 1]), 0.0f);
            s = fmaf(h, sW2v[4 * q + 1], s);
            h = fmaxf(uu.z + vv.z + fmaf(a, sC[4 * q + 2], sb1[4 * q + 2]), 0.0f);
            s = fmaf(h, sW2v[4 * q + 2], s);
            h = fmaxf(uu.w + vv.w + fmaf(a, sC[4 * q + 3], sb1[4 * q + 3]), 0.0f);
            s = fmaf(h, sW2v[4 * q + 3], s);
        }
        out[e] = 1.0f / (1.0f + expf(-s));
    }
}

extern "C" void kernel_launch(void* const* d_in, const int* in_sizes, int n_in,
                              void* d_out, int out_size, void* d_ws, size_t ws_size,
                              hipStream_t stream) {
    const float* x   = (const float*)d_in[0];
    const int*   ei  = (const int*)d_in[1];   // [2, E] int32
    const float* ea  = (const float*)d_in[2];
    // d_in[3] = num_nodes (device scalar, unused; N from in_sizes)
    const float* W1  = (const float*)d_in[4];
    const float* b1  = (const float*)d_in[5];
    const float* W2  = (const float*)d_in[6];
    const float* b2  = (const float*)d_in[7];
    const float* mW1 = (const float*)d_in[8];
    const float* mb1 = (const float*)d_in[9];
    const float* mW2 = (const float*)d_in[10];
    const float* mb2 = (const float*)d_in[11];
    float* out = (float*)d_out;

    int N = in_sizes[0] / 2;
    int E = in_sizes[2];
    const int* row = ei;
    const int* col = ei + E;

    float* ws   = (float*)d_ws;
    float* dinv = ws;                    // N      (deg, then dinv in place)
    float* xs   = ws + (size_t)N;        // 2N
    float* accx = ws + (size_t)3 * N;    // 2N
    float* hs2  = ws + (size_t)5 * N;    // 32N
    float* acc2 = ws + (size_t)37 * N;   // 32N
    float* ub   = ws + (size_t)69 * N;   // 16N
    float* vb   = ws + (size_t)85 * N;   // 16N   total 101N floats (~40.4 MB)

    hipMemsetAsync(dinv, 0, (size_t)N * sizeof(float), stream);

    int nb_n = (N + 255) / 256;
    k_deg  <<<1024, 256, 0, stream>>>(col, dinv, E);
    k_node1<<<nb_n, 256, 0, stream>>>(x, dinv, xs, accx, N);
    k_scat1<<<1024, 256, 0, stream>>>(row, col, xs, accx, E);
    k_node2<<<nb_n, 256, 0, stream>>>(accx, dinv, W1, b1, W2, hs2, acc2, N);
    k_scat2<<<2048, 256, 0, stream>>>(row, col, hs2, acc2, E);
    k_node3<<<nb_n, 256, 0, stream>>>(acc2, dinv, b2, mW1, ub, vb, N);
    k_edge <<<1024, 256, 0, stream>>>(row, col, ea, ub, vb, mW1, mb1, mW2, mb2, out, E);
}

// Round 2
// 547.315 us; speedup vs baseline: 1.2208x; 1.2208x over previous
//
#include <hip/hip_runtime.h>
#include <math.h>

// ---------------------------------------------------------------------------
// GCN (2->64->32) + edge MLP (65->16->1), N=100k, E=1.6M.
// R2: replace ALL f32 atomics with CSR (counting-sort on col) + gathers.
//   build CSR: count (int atomics) -> 3-kernel exclusive scan -> fill
//   L1: gather xs (2ch) per node, fuse W1/relu/W2 matmuls  -> hs2
//   L2: 32 lanes per node gather hs2 rows, fuse u/v matmul -> u,v
//   edge MLP: hid = relu(u[row]+v[col]+ea*c+mb1); out = sigmoid(hid@mW2+mb2)
// ---------------------------------------------------------------------------

__global__ void k_count(const int* __restrict__ col, int* __restrict__ degi, int E) {
    int stride = gridDim.x * blockDim.x;
    for (int e = blockIdx.x * blockDim.x + threadIdx.x; e < E; e += stride)
        atomicAdd(degi + col[e], 1);
}

// per-block exclusive scan of degi -> start, block totals -> bsum
__global__ void k_scan1(const int* __restrict__ degi, int* __restrict__ start,
                        int* __restrict__ bsum, int N) {
    __shared__ int sd[256];
    int t = threadIdx.x;
    int n = blockIdx.x * 256 + t;
    int d = (n < N) ? degi[n] : 0;
    sd[t] = d;
    __syncthreads();
    for (int off = 1; off < 256; off <<= 1) {
        int tv = (t >= off) ? sd[t - off] : 0;
        __syncthreads();
        sd[t] += tv;
        __syncthreads();
    }
    if (n < N) start[n] = sd[t] - d;           // exclusive within block
    if (t == 255) bsum[blockIdx.x] = sd[255];  // block total
}

// exclusive scan of bsum (nb <= 512) in one block
__global__ void k_scan2(int* __restrict__ bsum, int nb) {
    __shared__ int sd[512];
    int t = threadIdx.x;
    int d = (t < nb) ? bsum[t] : 0;
    sd[t] = d;
    __syncthreads();
    for (int off = 1; off < 512; off <<= 1) {
        int tv = (t >= off) ? sd[t - off] : 0;
        __syncthreads();
        sd[t] += tv;
        __syncthreads();
    }
    if (t < nb) bsum[t] = sd[t] - d;  // exclusive block offsets
}

// start += block offset; cursor = start; dinv = rsqrt(deg+1); xs = x*dinv
__global__ void k_scan3(int* __restrict__ start, const int* __restrict__ bsum,
                        int* __restrict__ cursor, const int* __restrict__ degi,
                        const float* __restrict__ x, float* __restrict__ dinv,
                        float* __restrict__ xs, int N) {
    int n = blockIdx.x * 256 + threadIdx.x;
    if (n >= N) return;
    int s = start[n] + bsum[blockIdx.x];
    start[n] = s;
    cursor[n] = s;
    float di = rsqrtf((float)degi[n] + 1.0f);
    dinv[n] = di;
    xs[2 * n] = x[2 * n] * di;
    xs[2 * n + 1] = x[2 * n + 1] * di;
}

__global__ void k_fill(const int* __restrict__ row, const int* __restrict__ col,
                       int* __restrict__ cursor, int* __restrict__ srcidx, int E) {
    int stride = gridDim.x * blockDim.x;
    for (int e = blockIdx.x * blockDim.x + threadIdx.x; e < E; e += stride) {
        int c = col[e];
        int p = atomicAdd(cursor + c, 1);
        srcidx[p] = row[e];
    }
}

// per node: agg xs over in-edges (+self), *dinv, W1+b1, relu, W2, *dinv -> hs2
__global__ void k_l1l2(const int* __restrict__ start, const int* __restrict__ degi,
                       const int* __restrict__ srcidx,
                       const float* __restrict__ xs, const float* __restrict__ dinv,
                       const float* __restrict__ W1, const float* __restrict__ b1,
                       const float* __restrict__ W2,
                       float* __restrict__ hs2, int N) {
    __shared__ float sW1[128], sb1[64], sW2[2048];
    for (int i = threadIdx.x; i < 128;  i += blockDim.x) sW1[i] = W1[i];
    for (int i = threadIdx.x; i < 64;   i += blockDim.x) sb1[i] = b1[i];
    for (int i = threadIdx.x; i < 2048; i += blockDim.x) sW2[i] = W2[i];
    __syncthreads();
    int n = blockIdx.x * 256 + threadIdx.x;
    if (n >= N) return;
    int s = start[n], cnt = degi[n];
    float a0 = xs[2 * n], a1 = xs[2 * n + 1];  // self-loop term
    for (int k = 0; k < cnt; ++k) {
        int r = srcidx[s + k];
        a0 += xs[2 * r];
        a1 += xs[2 * r + 1];
    }
    float di = dinv[n];
    a0 *= di; a1 *= di;
    float acc[32];
#pragma unroll
    for (int j = 0; j < 32; ++j) acc[j] = 0.0f;
    for (int k = 0; k < 64; ++k) {
        float h = fmaxf(fmaf(a0, sW1[k], fmaf(a1, sW1[64 + k], sb1[k])), 0.0f);
#pragma unroll
        for (int j = 0; j < 32; ++j) acc[j] = fmaf(h, sW2[k * 32 + j], acc[j]);
    }
    float4* op = (float4*)(hs2 + (size_t)n * 32);
#pragma unroll
    for (int q = 0; q < 8; ++q) {
        float4 t;
        t.x = acc[4 * q] * di; t.y = acc[4 * q + 1] * di;
        t.z = acc[4 * q + 2] * di; t.w = acc[4 * q + 3] * di;
        op[q] = t;
    }
}

// 32 lanes per node: gather-sum hs2 rows -> h2 = relu(sum*dinv+b2) -> LDS,
// then u = h2@A, v = h2@B  (A/B = mW1 rows 0..31 / 32..63)
__global__ void k_agg2uv(const int* __restrict__ start, const int* __restrict__ degi,
                         const int* __restrict__ srcidx,
                         const float* __restrict__ hs2, const float* __restrict__ dinv,
                         const float* __restrict__ b2, const float* __restrict__ mW1,
                         float* __restrict__ u, float* __restrict__ v, int N) {
    __shared__ float sA[512], sB[512], sb2[32];
    __shared__ float h2s[8][32];
    for (int i = threadIdx.x; i < 512; i += 256) { sA[i] = mW1[i]; sB[i] = mW1[512 + i]; }
    if (threadIdx.x < 32) sb2[threadIdx.x] = b2[threadIdx.x];
    __syncthreads();
    int g  = threadIdx.x >> 5;         // node group 0..7
    int ch = threadIdx.x & 31;         // channel lane
    int n  = blockIdx.x * 8 + g;
    if (n < N) {
        int s = start[n], cnt = degi[n];
        float acc = hs2[(size_t)n * 32 + ch];     // self loop
        for (int k = 0; k < cnt; ++k) {
            int r = srcidx[s + k];
            acc += hs2[(size_t)r * 32 + ch];
        }
        h2s[g][ch] = fmaxf(fmaf(acc, dinv[n], sb2[ch]), 0.0f);
    }
    __syncthreads();
    if (n >= N) return;
    // 32 lanes per node: lanes 0..15 compute u[i], 16..31 compute v[i-16]
    const float* M = (ch < 16) ? sA : sB;
    int i = ch & 15;
    float s0 = 0.0f;
#pragma unroll
    for (int j = 0; j < 32; ++j) s0 = fmaf(h2s[g][j], M[j * 16 + i], s0);
    if (ch < 16) u[(size_t)n * 16 + i] = s0;
    else         v[(size_t)n * 16 + i] = s0;
}

__global__ void k_edge(const int* __restrict__ row, const int* __restrict__ col,
                       const float* __restrict__ ea,
                       const float* __restrict__ u, const float* __restrict__ v,
                       const float* __restrict__ mW1, const float* __restrict__ mb1,
                       const float* __restrict__ mW2, const float* __restrict__ mb2,
                       float* __restrict__ out, int E) {
    __shared__ float sC[16], sb1[16], sW2v[16], sb2s;
    if (threadIdx.x < 16) {
        sC[threadIdx.x]   = mW1[64 * 16 + threadIdx.x];
        sb1[threadIdx.x]  = mb1[threadIdx.x];
        sW2v[threadIdx.x] = mW2[threadIdx.x];
    }
    if (threadIdx.x == 0) sb2s = mb2[0];
    __syncthreads();
    int stride = gridDim.x * blockDim.x;
    for (int e = blockIdx.x * blockDim.x + threadIdx.x; e < E; e += stride) {
        int r = row[e], c = col[e];
        float a = ea[e];
        const float4* up = (const float4*)(u + (size_t)r * 16);
        const float4* vp = (const float4*)(v + (size_t)c * 16);
        float s = sb2s;
#pragma unroll
        for (int q = 0; q < 4; ++q) {
            float4 uu = up[q];
            float4 vv = vp[q];
            float h;
            h = fmaxf(uu.x + vv.x + fmaf(a, sC[4 * q + 0], sb1[4 * q + 0]), 0.0f);
            s = fmaf(h, sW2v[4 * q + 0], s);
            h = fmaxf(uu.y + vv.y + fmaf(a, sC[4 * q + 1], sb1[4 * q + 1]), 0.0f);
            s = fmaf(h, sW2v[4 * q + 1], s);
            h = fmaxf(uu.z + vv.z + fmaf(a, sC[4 * q + 2], sb1[4 * q + 2]), 0.0f);
            s = fmaf(h, sW2v[4 * q + 2], s);
            h = fmaxf(uu.w + vv.w + fmaf(a, sC[4 * q + 3], sb1[4 * q + 3]), 0.0f);
            s = fmaf(h, sW2v[4 * q + 3], s);
        }
        out[e] = 1.0f / (1.0f + expf(-s));
    }
}

extern "C" void kernel_launch(void* const* d_in, const int* in_sizes, int n_in,
                              void* d_out, int out_size, void* d_ws, size_t ws_size,
                              hipStream_t stream) {
    const float* x   = (const float*)d_in[0];
    const int*   ei  = (const int*)d_in[1];
    const float* ea  = (const float*)d_in[2];
    const float* W1  = (const float*)d_in[4];
    const float* b1  = (const float*)d_in[5];
    const float* W2  = (const float*)d_in[6];
    const float* b2  = (const float*)d_in[7];
    const float* mW1 = (const float*)d_in[8];
    const float* mb1 = (const float*)d_in[9];
    const float* mW2 = (const float*)d_in[10];
    const float* mb2 = (const float*)d_in[11];
    float* out = (float*)d_out;

    int N = in_sizes[0] / 2;
    int E = in_sizes[2];
    const int* row = ei;
    const int* col = ei + E;

    // workspace layout (ints first, then 16B-aligned floats)
    int* degi   = (int*)d_ws;            // N
    int* start  = degi + N;              // N
    int* cursor = start + N;             // N
    int* bsum   = cursor + N;            // 1024
    int* srcidx = bsum + 1024;           // E
    float* dinv = (float*)(srcidx + E);  // N
    float* xs   = dinv + (size_t)N;      // 2N
    float* hs2  = xs + (size_t)2 * N;    // 32N
    float* u    = hs2 + (size_t)32 * N;  // 16N
    float* v    = u + (size_t)16 * N;    // 16N

    int nb_n = (N + 255) / 256;          // 391 for N=100k

    hipMemsetAsync(degi, 0, (size_t)N * sizeof(int), stream);
    k_count<<<1024, 256, 0, stream>>>(col, degi, E);
    k_scan1<<<nb_n, 256, 0, stream>>>(degi, start, bsum, N);
    k_scan2<<<1, 512, 0, stream>>>(bsum, nb_n);
    k_scan3<<<nb_n, 256, 0, stream>>>(start, bsum, cursor, degi, x, dinv, xs, N);
    k_fill <<<1024, 256, 0, stream>>>(row, col, cursor, srcidx, E);
    k_l1l2 <<<nb_n, 256, 0, stream>>>(start, degi, srcidx, xs, dinv, W1, b1, W2, hs2, N);
    k_agg2uv<<<(N + 7) / 8, 256, 0, stream>>>(start, degi, srcidx, hs2, dinv, b2, mW1, u, v, N);
    k_edge <<<1024, 256, 0, stream>>>(row, col, ea, u, v, mW1, mb1, mW2, mb2, out, E);
}

// Round 4
// 490.084 us; speedup vs baseline: 1.3634x; 1.1168x over previous
//
#include <hip/hip_runtime.h>
#include <math.h>

// ---------------------------------------------------------------------------
// GCN (2->64->32) + edge MLP (65->16->1), N=100k, E=1.6M.
// R3 (resubmit; GPU was unavailable): fix k_fill's 16x write amplification:
//   - phase-windowed fill: process col-ranges (~16k nodes) per phase so the
//     srcidx write window (~1MB) stays L2-resident and lines fill before
//     eviction. Edge list re-reads hit L2/L3.
//   - pad atomic counters (deg/cursor) to one per 128B line.
// ---------------------------------------------------------------------------

__global__ void k_count(const int* __restrict__ col, int* __restrict__ degp,
                        int E, int pshift) {
    int stride = gridDim.x * blockDim.x;
    for (int e = blockIdx.x * blockDim.x + threadIdx.x; e < E; e += stride)
        atomicAdd(degp + ((size_t)col[e] << pshift), 1);
}

// per-block exclusive scan of degp -> start, block totals -> bsum
__global__ void k_scan1(const int* __restrict__ degp, int* __restrict__ start,
                        int* __restrict__ bsum, int N, int pshift) {
    __shared__ int sd[256];
    int t = threadIdx.x;
    int n = blockIdx.x * 256 + t;
    int d = (n < N) ? degp[(size_t)n << pshift] : 0;
    sd[t] = d;
    __syncthreads();
    for (int off = 1; off < 256; off <<= 1) {
        int tv = (t >= off) ? sd[t - off] : 0;
        __syncthreads();
        sd[t] += tv;
        __syncthreads();
    }
    if (n < N) start[n] = sd[t] - d;
    if (t == 255) bsum[blockIdx.x] = sd[255];
}

__global__ void k_scan2(int* __restrict__ bsum, int nb) {
    __shared__ int sd[512];
    int t = threadIdx.x;
    int d = (t < nb) ? bsum[t] : 0;
    sd[t] = d;
    __syncthreads();
    for (int off = 1; off < 512; off <<= 1) {
        int tv = (t >= off) ? sd[t - off] : 0;
        __syncthreads();
        sd[t] += tv;
        __syncthreads();
    }
    if (t < nb) bsum[t] = sd[t] - d;
}

// finalize start, init padded cursor, compact deg, dinv, xs
__global__ void k_scan3(int* __restrict__ start, const int* __restrict__ bsum,
                        int* __restrict__ curp, int* __restrict__ degc,
                        const int* __restrict__ degp,
                        const float* __restrict__ x, float* __restrict__ dinv,
                        float* __restrict__ xs, int N, int pshift) {
    int n = blockIdx.x * 256 + threadIdx.x;
    if (n >= N) return;
    int s = start[n] + bsum[blockIdx.x];
    start[n] = s;
    curp[(size_t)n << pshift] = s;
    int d = degp[(size_t)n << pshift];
    degc[n] = d;
    float di = rsqrtf((float)d + 1.0f);
    dinv[n] = di;
    xs[2 * n] = x[2 * n] * di;
    xs[2 * n + 1] = x[2 * n + 1] * di;
}

// phase-windowed fill: phase ph handles cols in [ph<<wshift, (ph+1)<<wshift)
__global__ void k_fill(const int* __restrict__ row, const int* __restrict__ col,
                       int* __restrict__ curp, int* __restrict__ srcidx,
                       int E, int pshift, int wshift, int nph) {
    int stride = gridDim.x * blockDim.x;
    int tid0 = blockIdx.x * blockDim.x + threadIdx.x;
    for (int ph = 0; ph < nph; ++ph) {
        for (int e = tid0; e < E; e += stride) {
            int c = col[e];
            if ((c >> wshift) == ph) {
                int p = atomicAdd(curp + ((size_t)c << pshift), 1);
                srcidx[p] = row[e];
            }
        }
    }
}

// per node: agg xs over in-edges (+self), *dinv, W1+b1, relu, W2, *dinv -> hs2
__global__ void k_l1l2(const int* __restrict__ start, const int* __restrict__ degc,
                       const int* __restrict__ srcidx,
                       const float* __restrict__ xs, const float* __restrict__ dinv,
                       const float* __restrict__ W1, const float* __restrict__ b1,
                       const float* __restrict__ W2,
                       float* __restrict__ hs2, int N) {
    __shared__ float sW1[128], sb1[64], sW2[2048];
    for (int i = threadIdx.x; i < 128;  i += blockDim.x) sW1[i] = W1[i];
    for (int i = threadIdx.x; i < 64;   i += blockDim.x) sb1[i] = b1[i];
    for (int i = threadIdx.x; i < 2048; i += blockDim.x) sW2[i] = W2[i];
    __syncthreads();
    int n = blockIdx.x * 256 + threadIdx.x;
    if (n >= N) return;
    int s = start[n], cnt = degc[n];
    float a0 = xs[2 * n], a1 = xs[2 * n + 1];  // self-loop term
    for (int k = 0; k < cnt; ++k) {
        int r = srcidx[s + k];
        a0 += xs[2 * r];
        a1 += xs[2 * r + 1];
    }
    float di = dinv[n];
    a0 *= di; a1 *= di;
    float acc[32];
#pragma unroll
    for (int j = 0; j < 32; ++j) acc[j] = 0.0f;
    for (int k = 0; k < 64; ++k) {
        float h = fmaxf(fmaf(a0, sW1[k], fmaf(a1, sW1[64 + k], sb1[k])), 0.0f);
#pragma unroll
        for (int j = 0; j < 32; ++j) acc[j] = fmaf(h, sW2[k * 32 + j], acc[j]);
    }
    float4* op = (float4*)(hs2 + (size_t)n * 32);
#pragma unroll
    for (int q = 0; q < 8; ++q) {
        float4 t;
        t.x = acc[4 * q] * di; t.y = acc[4 * q + 1] * di;
        t.z = acc[4 * q + 2] * di; t.w = acc[4 * q + 3] * di;
        op[q] = t;
    }
}

// 32 lanes per node: gather-sum hs2 rows -> h2 = relu(sum*dinv+b2) -> LDS,
// then u = h2@A, v = h2@B  (A/B = mW1 rows 0..31 / 32..63)
__global__ void k_agg2uv(const int* __restrict__ start, const int* __restrict__ degc,
                         const int* __restrict__ srcidx,
                         const float* __restrict__ hs2, const float* __restrict__ dinv,
                         const float* __restrict__ b2, const float* __restrict__ mW1,
                         float* __restrict__ u, float* __restrict__ v, int N) {
    __shared__ float sA[512], sB[512], sb2[32];
    __shared__ float h2s[8][32];
    for (int i = threadIdx.x; i < 512; i += 256) { sA[i] = mW1[i]; sB[i] = mW1[512 + i]; }
    if (threadIdx.x < 32) sb2[threadIdx.x] = b2[threadIdx.x];
    __syncthreads();
    int g  = threadIdx.x >> 5;
    int ch = threadIdx.x & 31;
    int n  = blockIdx.x * 8 + g;
    if (n < N) {
        int s = start[n], cnt = degc[n];
        float acc = hs2[(size_t)n * 32 + ch];     // self loop
        for (int k = 0; k < cnt; ++k) {
            int r = srcidx[s + k];
            acc += hs2[(size_t)r * 32 + ch];
        }
        h2s[g][ch] = fmaxf(fmaf(acc, dinv[n], sb2[ch]), 0.0f);
    }
    __syncthreads();
    if (n >= N) return;
    const float* M = (ch < 16) ? sA : sB;
    int i = ch & 15;
    float s0 = 0.0f;
#pragma unroll
    for (int j = 0; j < 32; ++j) s0 = fmaf(h2s[g][j], M[j * 16 + i], s0);
    if (ch < 16) u[(size_t)n * 16 + i] = s0;
    else         v[(size_t)n * 16 + i] = s0;
}

__global__ void k_edge(const int* __restrict__ row, const int* __restrict__ col,
                       const float* __restrict__ ea,
                       const float* __restrict__ u, const float* __restrict__ v,
                       const float* __restrict__ mW1, const float* __restrict__ mb1,
                       const float* __restrict__ mW2, const float* __restrict__ mb2,
                       float* __restrict__ out, int E) {
    __shared__ float sC[16], sb1[16], sW2v[16], sb2s;
    if (threadIdx.x < 16) {
        sC[threadIdx.x]   = mW1[64 * 16 + threadIdx.x];
        sb1[threadIdx.x]  = mb1[threadIdx.x];
        sW2v[threadIdx.x] = mW2[threadIdx.x];
    }
    if (threadIdx.x == 0) sb2s = mb2[0];
    __syncthreads();
    int stride = gridDim.x * blockDim.x;
    for (int e = blockIdx.x * blockDim.x + threadIdx.x; e < E; e += stride) {
        int r = row[e], c = col[e];
        float a = ea[e];
        const float4* up = (const float4*)(u + (size_t)r * 16);
        const float4* vp = (const float4*)(v + (size_t)c * 16);
        float s = sb2s;
#pragma unroll
        for (int q = 0; q < 4; ++q) {
            float4 uu = up[q];
            float4 vv = vp[q];
            float h;
            h = fmaxf(uu.x + vv.x + fmaf(a, sC[4 * q + 0], sb1[4 * q + 0]), 0.0f);
            s = fmaf(h, sW2v[4 * q + 0], s);
            h = fmaxf(uu.y + vv.y + fmaf(a, sC[4 * q + 1], sb1[4 * q + 1]), 0.0f);
            s = fmaf(h, sW2v[4 * q + 1], s);
            h = fmaxf(uu.z + vv.z + fmaf(a, sC[4 * q + 2], sb1[4 * q + 2]), 0.0f);
            s = fmaf(h, sW2v[4 * q + 2], s);
            h = fmaxf(uu.w + vv.w + fmaf(a, sC[4 * q + 3], sb1[4 * q + 3]), 0.0f);
            s = fmaf(h, sW2v[4 * q + 3], s);
        }
        out[e] = 1.0f / (1.0f + expf(-s));
    }
}

extern "C" void kernel_launch(void* const* d_in, const int* in_sizes, int n_in,
                              void* d_out, int out_size, void* d_ws, size_t ws_size,
                              hipStream_t stream) {
    const float* x   = (const float*)d_in[0];
    const int*   ei  = (const int*)d_in[1];
    const float* ea  = (const float*)d_in[2];
    const float* W1  = (const float*)d_in[4];
    const float* b1  = (const float*)d_in[5];
    const float* W2  = (const float*)d_in[6];
    const float* b2  = (const float*)d_in[7];
    const float* mW1 = (const float*)d_in[8];
    const float* mb1 = (const float*)d_in[9];
    const float* mW2 = (const float*)d_in[10];
    const float* mb2 = (const float*)d_in[11];
    float* out = (float*)d_out;

    int N = in_sizes[0] / 2;
    int E = in_sizes[2];
    const int* row = ei;
    const int* col = ei + E;

    // pick counter padding shift by available workspace
    auto need = [&](int ps) -> size_t {
        size_t ints = 2 * ((size_t)N << ps) + 2 * (size_t)N + 1024 + (size_t)E;
        size_t flts = (size_t)67 * N;
        return (ints + flts) * 4;
    };
    int pshift = 0;
    if (need(5) <= ws_size) pshift = 5;        // 128B line per counter
    else if (need(4) <= ws_size) pshift = 4;   // 64B line per counter

    // phase window: ~8 phases over the node range
    int clog = 0; while ((1u << clog) < (unsigned)N) ++clog;
    int wshift = clog > 3 ? clog - 3 : 0;
    int nph = ((N - 1) >> wshift) + 1;

    int* degp   = (int*)d_ws;                    // N<<pshift
    int* curp   = degp + ((size_t)N << pshift);  // N<<pshift
    int* start  = curp + ((size_t)N << pshift);  // N
    int* degc   = start + N;                     // N
    int* bsum   = degc + N;                      // 1024
    int* srcidx = bsum + 1024;                   // E
    float* dinv = (float*)(srcidx + E);          // N
    float* xs   = dinv + (size_t)N;              // 2N
    float* hs2  = xs + (size_t)2 * N;            // 32N
    float* u    = hs2 + (size_t)32 * N;          // 16N
    float* v    = u + (size_t)16 * N;            // 16N

    int nb_n = (N + 255) / 256;

    hipMemsetAsync(degp, 0, ((size_t)N << pshift) * sizeof(int), stream);
    k_count<<<1024, 256, 0, stream>>>(col, degp, E, pshift);
    k_scan1<<<nb_n, 256, 0, stream>>>(degp, start, bsum, N, pshift);
    k_scan2<<<1, 512, 0, stream>>>(bsum, nb_n);
    k_scan3<<<nb_n, 256, 0, stream>>>(start, bsum, curp, degc, degp, x, dinv, xs, N, pshift);
    k_fill <<<1024, 256, 0, stream>>>(row, col, curp, srcidx, E, pshift, wshift, nph);
    k_l1l2 <<<nb_n, 256, 0, stream>>>(start, degc, srcidx, xs, dinv, W1, b1, W2, hs2, N);
    k_agg2uv<<<(N + 7) / 8, 256, 0, stream>>>(start, degc, srcidx, hs2, dinv, b2, mW1, u, v, N);
    k_edge <<<1024, 256, 0, stream>>>(row, col, ea, u, v, mW1, mb1, mW2, mb2, out, E);
}